// Round 12
// baseline (482.406 us; speedup 1.0000x reference)
//
#include <hip/hip_runtime.h>
#include <math.h>

// B=32, C=D=64, H=W=64, K=1024
constexpr int K_CODES = 1024;
constexpr int D_DIM   = 64;
constexpr int HW      = 4096;
constexpr int NPOS    = 131072;
constexpr int CHW     = 262144;

typedef short bf16x8 __attribute__((ext_vector_type(8)));
typedef float f32x4  __attribute__((ext_vector_type(4)));

__device__ __forceinline__ unsigned short f2bf(float f) {
    unsigned u = __float_as_uint(f);
    return (unsigned short)((u + 0x7FFFu + ((u >> 16) & 1u)) >> 16);
}
__device__ __forceinline__ unsigned mapf(float f) {
    unsigned u = __float_as_uint(f);
    return u ^ ((unsigned)((int)u >> 31) | 0x80000000u);
}
__device__ __forceinline__ unsigned long long umin64(unsigned long long a,
                                                     unsigned long long b) {
    return a < b ? a : b;
}
// XOR slot swizzle within each 8-float4 (128B) row: spreads same-column
// b128 reads across the 8 slots -> LDS BW-floor instead of 16-way conflict.
__device__ __forceinline__ int swz(int f) {
    return (f & ~7) | ((f ^ (f >> 3)) & 7);
}

// ws layout: [0..1023] c2 fp32 | [1024..2047] hist fp32 | byte 8192..: bf16 cb (128 KB)
__global__ void vq_prep(const float* __restrict__ cb, float* __restrict__ ws) {
    int k = blockIdx.x * blockDim.x + threadIdx.x;
    if (k < K_CODES) {
        const float4* row = reinterpret_cast<const float4*>(cb + k * D_DIM);
        float s0 = 0.f, s1 = 0.f, s2 = 0.f, s3 = 0.f;
#pragma unroll
        for (int i = 0; i < 16; ++i) {
            float4 v = row[i];
            s0 = fmaf(v.x, v.x, s0);
            s1 = fmaf(v.y, v.y, s1);
            s2 = fmaf(v.z, v.z, s2);
            s3 = fmaf(v.w, v.w, s3);
        }
        ws[k] = (s0 + s1) + (s2 + s3);
        ws[K_CODES + k] = 0.0f;
        unsigned short* cbh = (unsigned short*)(ws + 2048);
#pragma unroll
        for (int d = 0; d < D_DIM; ++d) cbh[k * D_DIM + d] = f2bf(cb[k * D_DIM + d]);
    }
}

// r11 diagnosis: pipes idle; real cost = 2GB L2 codebook re-reads (no wave
// sharing) + 8.4M-transaction scalar gather epilogue. r12: LDS-chunked
// codebook shared by all 4 waves (swizzled, prefetched), coalesced float4
// gather through LDS. Distance math / thresholds / tie-break bit-identical.
#define FOR_R(M) M(0) M(1) M(2) M(3)

__global__ __launch_bounds__(256)
__attribute__((amdgpu_waves_per_eu(1, 4)))
void vq_main(const float* __restrict__ in, const float* __restrict__ cb,
             float* __restrict__ out, float* __restrict__ ws) {
    float* hist = ws + K_CODES;

    // manual LDS pool (qbuf overlays lds_cb+c2s in the epilogue)
    __shared__ __align__(16) unsigned char pool[37888];
    float4* lds_cb = (float4*)pool;                       // [1024] 16 KB
    float*  c2s    = (float*)(pool + 16384);              // [1024] 4 KB
    float*  x_lds  = (float*)(pool + 20480);              // [64][65] 16640 B
    unsigned long long* win = (unsigned long long*)(pool + 37120); // [64]
    float*  x2_lds = (float*)(pool + 37632);              // [64]
    float*  qbuf   = (float*)pool;                        // [64][65] (epilogue)
#define XL(r, c) x_lds[(r) * 65 + (c)]

    const int t   = threadIdx.x;
    const int l   = t & 63;
    const int w   = t >> 6;
    const int nbase = blockIdx.x * 64;
    const int b   = nbase >> 12;
    const int hw0 = nbase & 4095;
    const float* xb = in + (size_t)b * CHW + hw0;

    // stage x (coalesced) + c2
#pragma unroll
    for (int cc = 0; cc < 16; ++cc) {
        int c = w * 16 + cc;
        XL(l, c) = xb[(size_t)c * HW + l];
    }
#pragma unroll
    for (int j = 0; j < 4; ++j) c2s[t + j * 256] = ws[t + j * 256];
    __syncthreads();

    // x2 in the exact 4-partial order (bit-identical to rounds 1-11)
    if (t < 64) {
        float s0 = 0.f, s1 = 0.f, s2 = 0.f, s3 = 0.f;
#pragma unroll
        for (int i = 0; i < 16; ++i) {
            s0 = fmaf(XL(t, 4 * i + 0), XL(t, 4 * i + 0), s0);
            s1 = fmaf(XL(t, 4 * i + 1), XL(t, 4 * i + 1), s1);
            s2 = fmaf(XL(t, 4 * i + 2), XL(t, 4 * i + 2), s2);
            s3 = fmaf(XL(t, 4 * i + 3), XL(t, 4 * i + 3), s3);
        }
        x2_lds[t] = (s0 + s1) + (s2 + s3);
    }
    __syncthreads();

    const int nlo = l & 15;   // code within tile
    const int kq  = l >> 4;   // k-quarter
    const int sw0 = kq ^ (nlo & 7);         // swizzled slot for b0
    const int sw1 = (kq + 4) ^ (nlo & 7);   // swizzled slot for b1

    bf16x8 a0, a1;
#pragma unroll
    for (int j = 0; j < 8; ++j) {
        a0[j] = (short)f2bf(XL(w * 16 + nlo, kq * 8 + j));
        a1[j] = (short)f2bf(XL(w * 16 + nlo, kq * 8 + 32 + j));
    }
    const int prow0 = w * 16 + kq * 4, prow1 = prow0 + 1;
    const int prow2 = prow0 + 2,       prow3 = prow0 + 3;
    const float x2r0 = x2_lds[prow0], x2r1 = x2_lds[prow1];
    const float x2r2 = x2_lds[prow2], x2r3 = x2_lds[prow3];

    const float4* cbv4 = (const float4*)(ws + 2048);  // bf16 cb as 8192 float4

    // ================= Phase A: approx min =================
    float fm0 = INFINITY, fm1 = INFINITY, fm2 = INFINITY, fm3 = INFINITY;
    {
        float4 v0 = cbv4[t], v1 = cbv4[t + 256], v2 = cbv4[t + 512], v3 = cbv4[t + 768];
        lds_cb[swz(t)] = v0;       lds_cb[swz(t + 256)] = v1;
        lds_cb[swz(t + 512)] = v2; lds_cb[swz(t + 768)] = v3;
    }
    __syncthreads();
#pragma unroll 1
    for (int ch = 0; ch < 8; ++ch) {
        float4 p0, p1, p2, p3;
        const bool more = (ch < 7);
        if (more) {
            int base = (ch + 1) * 1024;
            p0 = cbv4[base + t];       p1 = cbv4[base + t + 256];
            p2 = cbv4[base + t + 512]; p3 = cbv4[base + t + 768];
        }
#pragma unroll
        for (int tt = 0; tt < 8; ++tt) {
            const int rowbase = tt * 128 + nlo * 8;
            bf16x8 b0 = *(const bf16x8*)&lds_cb[rowbase + sw0];
            bf16x8 b1 = *(const bf16x8*)&lds_cb[rowbase + sw1];
            f32x4 acc = {0.f, 0.f, 0.f, 0.f};
            acc = __builtin_amdgcn_mfma_f32_16x16x32_bf16(a0, b0, acc, 0, 0, 0);
            acc = __builtin_amdgcn_mfma_f32_16x16x32_bf16(a1, b1, acc, 0, 0, 0);
            const float c2n = c2s[(ch * 8 + tt) * 16 + nlo];
#define UPD(r) { float sc = fmaf(-2.0f, acc[r], c2n); fm##r = fminf(fm##r, sc); }
            FOR_R(UPD)
#undef UPD
        }
        __syncthreads();
        if (more) {
            lds_cb[swz(t)] = p0;       lds_cb[swz(t + 256)] = p1;
            lds_cb[swz(t + 512)] = p2; lds_cb[swz(t + 768)] = p3;
        }
        __syncthreads();
    }
#define REDA(r) { \
    fm##r = fminf(fm##r, __shfl_xor(fm##r, 1, 16)); \
    fm##r = fminf(fm##r, __shfl_xor(fm##r, 2, 16)); \
    fm##r = fminf(fm##r, __shfl_xor(fm##r, 4, 16)); \
    fm##r = fminf(fm##r, __shfl_xor(fm##r, 8, 16)); }
    FOR_R(REDA)
#undef REDA
    const float thr0 = fm0 + (0.02f * sqrtf(x2r0) + 0.02f);
    const float thr1 = fm1 + (0.02f * sqrtf(x2r1) + 0.02f);
    const float thr2 = fm2 + (0.02f * sqrtf(x2r2) + 0.02f);
    const float thr3 = fm3 + (0.02f * sqrtf(x2r3) + 0.02f);

    // ================= Phase B: exact verify =================
    unsigned long long w0 = ~0ull, w1 = ~0ull, w2 = ~0ull, w3 = ~0ull;
    {
        float4 v0 = cbv4[t], v1 = cbv4[t + 256], v2 = cbv4[t + 512], v3 = cbv4[t + 768];
        lds_cb[swz(t)] = v0;       lds_cb[swz(t + 256)] = v1;
        lds_cb[swz(t + 512)] = v2; lds_cb[swz(t + 768)] = v3;
    }
    __syncthreads();
#pragma unroll 1
    for (int ch = 0; ch < 8; ++ch) {
        float4 p0, p1, p2, p3;
        const bool more = (ch < 7);
        if (more) {
            int base = (ch + 1) * 1024;
            p0 = cbv4[base + t];       p1 = cbv4[base + t + 256];
            p2 = cbv4[base + t + 512]; p3 = cbv4[base + t + 768];
        }
#pragma unroll
        for (int tt = 0; tt < 8; ++tt) {
            const int rowbase = tt * 128 + nlo * 8;
            bf16x8 b0 = *(const bf16x8*)&lds_cb[rowbase + sw0];
            bf16x8 b1 = *(const bf16x8*)&lds_cb[rowbase + sw1];
            f32x4 acc = {0.f, 0.f, 0.f, 0.f};
            acc = __builtin_amdgcn_mfma_f32_16x16x32_bf16(a0, b0, acc, 0, 0, 0);
            acc = __builtin_amdgcn_mfma_f32_16x16x32_bf16(a1, b1, acc, 0, 0, 0);
            const int   n   = (ch * 8 + tt) * 16 + nlo;
            const float c2n = c2s[n];
#define VER(r) { \
            float sc = fmaf(-2.0f, acc[r], c2n); \
            if (sc <= thr##r) { \
                const float* xr = x_lds + prow##r * 65; \
                const float4* cr = (const float4*)(cb + n * D_DIM); \
                float d0 = 0.f, d1 = 0.f, d2 = 0.f, d3 = 0.f; \
                _Pragma("unroll") \
                for (int i = 0; i < 16; ++i) { \
                    float4 v = cr[i]; \
                    d0 = fmaf(xr[4 * i + 0], v.x, d0); \
                    d1 = fmaf(xr[4 * i + 1], v.y, d1); \
                    d2 = fmaf(xr[4 * i + 2], v.z, d2); \
                    d3 = fmaf(xr[4 * i + 3], v.w, d3); } \
                float dot  = (d0 + d1) + (d2 + d3); \
                float dist = (x2r##r - 2.0f * dot) + c2n; \
                unsigned long long pk = \
                    ((unsigned long long)mapf(dist) << 32) | (unsigned)n; \
                w##r = umin64(w##r, pk); } }
            FOR_R(VER)
#undef VER
        }
        __syncthreads();
        if (more) {
            lds_cb[swz(t)] = p0;       lds_cb[swz(t + 256)] = p1;
            lds_cb[swz(t + 512)] = p2; lds_cb[swz(t + 768)] = p3;
        }
        __syncthreads();
    }
#define REDB(r) { \
    w##r = umin64(w##r, __shfl_xor(w##r, 1, 16)); \
    w##r = umin64(w##r, __shfl_xor(w##r, 2, 16)); \
    w##r = umin64(w##r, __shfl_xor(w##r, 4, 16)); \
    w##r = umin64(w##r, __shfl_xor(w##r, 8, 16)); }
    FOR_R(REDB)
#undef REDB
    if (nlo == 0) {
        win[prow0] = w0; win[prow1] = w1; win[prow2] = w2; win[prow3] = w3;
    }
    __syncthreads();

    // ============ epilogue: coalesced gather via LDS handoff ============
    {   // 4 lanes per position read the winner row as float4 (coalesced)
        const int p = t >> 2, j = t & 3;
        const int fidx = (int)(win[p] & 0xFFFFFFFFu);
        const float4* cr = (const float4*)(cb + fidx * D_DIM);
#pragma unroll
        for (int i = 0; i < 4; ++i) {
            float4 v = cr[j * 4 + i];
            qbuf[p * 65 + j * 16 + i * 4 + 0] = v.x;
            qbuf[p * 65 + j * 16 + i * 4 + 1] = v.y;
            qbuf[p * 65 + j * 16 + i * 4 + 2] = v.z;
            qbuf[p * 65 + j * 16 + i * 4 + 3] = v.w;
        }
    }
    __syncthreads();
    float* ob = out + (size_t)b * CHW + hw0;
#pragma unroll
    for (int cc = 0; cc < 16; ++cc) {
        int c = w * 16 + cc;
        float x = XL(l, c);
        float q = qbuf[l * 65 + c];
        ob[(size_t)c * HW + l] = x + (q - x);
    }
    if (t < 64) atomicAdd(&hist[(int)(win[t] & 0xFFFFFFFFu)], 1.0f);
#undef XL
}

// perplexity: one block, 1024 threads (16 waves)
__global__ void vq_ppl(const float* __restrict__ ws, float* __restrict__ outp) {
    __shared__ float red[16];
    int t = threadIdx.x;
    float e = ws[K_CODES + t] * (1.0f / (float)NPOS);
    float term = e * logf(e + 1e-10f);
#pragma unroll
    for (int off = 32; off > 0; off >>= 1)
        term += __shfl_down(term, off, 64);
    int lane = t & 63, wid = t >> 6;
    if (lane == 0) red[wid] = term;
    __syncthreads();
    if (t == 0) {
        float s = 0.f;
#pragma unroll
        for (int i = 0; i < 16; ++i) s += red[i];
        *outp = expf(-s);
    }
}

extern "C" void kernel_launch(void* const* d_in, const int* in_sizes, int n_in,
                              void* d_out, int out_size, void* d_ws, size_t ws_size,
                              hipStream_t stream) {
    const float* in = (const float*)d_in[0];   // [32,64,64,64] fp32
    const float* cb = (const float*)d_in[1];   // [1024,64] fp32
    float* out = (float*)d_out;                // quantized [8388608] + ppl [1]
    float* ws  = (float*)d_ws;                 // 8 KB + 128 KB bf16 codebook

    vq_prep<<<4, 256, 0, stream>>>(cb, ws);
    vq_main<<<NPOS / 64, 256, 0, stream>>>(in, cb, out, ws);
    vq_ppl<<<1, 1024, 0, stream>>>(ws, out + (size_t)8388608);
}